// Round 3
// baseline (271.593 us; speedup 1.0000x reference)
//
#include <hip/hip_runtime.h>
#include <cmath>

// CapsuleLayer routing, B=64, Ni=2048, Di=16, No=32, Do=16 (fp32 in/out).
// R3: MFMA split-bf16 GEMM. Key identities:
//  - routing coefficients c2[b,n,o] depend only on hsum = sum_d uhat (local per (b,n))
//  - x = x_hi + x_lo, W = W_hi + W_lo (bf16 RNE splits); pack split into K:
//      D  = mfma16x16x32(A=[x_hi|x_lo], B=[W_lo;W_lo], 0)
//      D +=| mfma16x16x32(A,            B=[W_hi;W_hi], D)
//    = (x_hi+x_lo)(W_hi+W_lo) exactly (all 4 cross terms), rel err ~2^-16.
// W never touches LDS: each wave global-loads its o-slice fp32 directly in
// B-fragment lane order, converts in-reg, Wd via 16-lane shuffle tree.

#define NI 2048
#define NG 8

typedef short bf16x8 __attribute__((ext_vector_type(8)));
typedef float f32x4 __attribute__((ext_vector_type(4)));

static __device__ __forceinline__ unsigned short f2bf(float f) {
  unsigned u = __float_as_uint(f);
  u += 0x7FFFu + ((u >> 16) & 1u);
  return (unsigned short)(u >> 16);
}
static __device__ __forceinline__ float bf2f(unsigned short h) {
  return __uint_as_float(((unsigned)h) << 16);
}

// grid 512 = 256 n-groups x 2 b-halves; block 512 = 8 waves; wave owns 4 o's.
__global__ __launch_bounds__(512, 4) void caps_fused_kernel(
    const float* __restrict__ x, const float* __restrict__ W,
    float* __restrict__ partial)
{
  const int bx = blockIdx.x;
  const int ng = bx >> 1, bh = bx & 1;
  const int t = threadIdx.x;
  const int wv = t >> 6, l = t & 63;
  const int q = l >> 4, dq = l & 15, qh = q & 1;
  const int bl = t >> 4, xi = t & 15;          // staging/routing mapping
  const int bg = bh * 32 + bl;                  // global b for staging

  // parity-buffered staging (A(n+1) may overlap D(n) across waves)
  __shared__ __align__(16) unsigned short XS[2][32 * 40]; // [b][hi16|lo16], 80B rows
  __shared__ float XSf[2][32 * 17];                        // fp32 x for routing
  __shared__ __align__(16) float WdS[2][32 * 20];          // Wd[o][i], 80B rows
  __shared__ __align__(16) float c2T[32 * 36];             // c2T[o][b_local]

  float acc[4][2][4];
  #pragma unroll
  for (int oo = 0; oo < 4; ++oo)
    #pragma unroll
    for (int bb = 0; bb < 2; ++bb)
      #pragma unroll
      for (int r = 0; r < 4; ++r) acc[oo][bb][r] = 0.f;

  const int n0 = ng * NG;
  // initial W/x loads (B-fragment order: lane(d=dq, k-half=qh) -> 8 fp32)
  float4 wa[4], wb[4];
  #pragma unroll
  for (int oo = 0; oo < 4; ++oo) {
    const int o = wv * 4 + oo;
    const float* wp = W + (size_t)n0 * 8192 + o * 256 + dq * 16 + qh * 8;
    wa[oo] = *(const float4*)wp;
    wb[oo] = *(const float4*)(wp + 4);
  }
  float xreg = x[(size_t)bg * (NI * 16) + n0 * 16 + xi];

  #pragma unroll 1
  for (int nn = 0; nn < NG; ++nn) {
    const int p = nn & 1;
    // ---------- Phase A: stage x (fp32 + split bf16), Wd via shuffle tree ----------
    {
      unsigned short hi = f2bf(xreg);
      unsigned short lo = f2bf(xreg - bf2f(hi));
      XSf[p][bl * 17 + xi] = xreg;
      XS[p][bl * 40 + xi] = hi;
      XS[p][bl * 40 + 16 + xi] = lo;
    }
    #pragma unroll
    for (int oo = 0; oo < 4; ++oo) {
      float s[8] = {wa[oo].x, wa[oo].y, wa[oo].z, wa[oo].w,
                    wb[oo].x, wb[oo].y, wb[oo].z, wb[oo].w};
      #pragma unroll
      for (int j = 0; j < 8; ++j) {
        s[j] += __shfl_xor(s[j], 1);
        s[j] += __shfl_xor(s[j], 2);
        s[j] += __shfl_xor(s[j], 4);
        s[j] += __shfl_xor(s[j], 8);
      }
      if (dq == 0 && q < 2) {   // lanes 0 (i 0-7) and 16 (i 8-15) hold the d-sums
        const int o = wv * 4 + oo;
        *(float4*)&WdS[p][o * 20 + qh * 8]     = make_float4(s[0], s[1], s[2], s[3]);
        *(float4*)&WdS[p][o * 20 + qh * 8 + 4] = make_float4(s[4], s[5], s[6], s[7]);
      }
    }
    if (nn < NG - 1)
      xreg = x[(size_t)bg * (NI * 16) + (n0 + nn + 1) * 16 + xi];
    __syncthreads();

    // ---------- Phase C: routing chain -> c2T ----------
    {
      float h0 = 0.f, h1 = 0.f;
      #pragma unroll
      for (int i = 0; i < 16; ++i) {
        float xv = XSf[p][bl * 17 + i];
        h0 += WdS[p][xi * 20 + i] * xv;
        h1 += WdS[p][(xi + 16) * 20 + i] * xv;
      }
      // b1 = h/32; c1 = softmax(b1); b2 = b1 + c1*h; c2 = softmax(b2)
      float b1_0 = h0 * 0.03125f, b1_1 = h1 * 0.03125f;
      float mx = fmaxf(b1_0, b1_1);
      mx = fmaxf(mx, __shfl_xor(mx, 1)); mx = fmaxf(mx, __shfl_xor(mx, 2));
      mx = fmaxf(mx, __shfl_xor(mx, 4)); mx = fmaxf(mx, __shfl_xor(mx, 8));
      float e0 = __expf(b1_0 - mx), e1 = __expf(b1_1 - mx);
      float S = e0 + e1;
      S += __shfl_xor(S, 1); S += __shfl_xor(S, 2);
      S += __shfl_xor(S, 4); S += __shfl_xor(S, 8);
      float inv = 1.0f / S;
      float b2_0 = b1_0 + e0 * inv * h0, b2_1 = b1_1 + e1 * inv * h1;
      float mx2 = fmaxf(b2_0, b2_1);
      mx2 = fmaxf(mx2, __shfl_xor(mx2, 1)); mx2 = fmaxf(mx2, __shfl_xor(mx2, 2));
      mx2 = fmaxf(mx2, __shfl_xor(mx2, 4)); mx2 = fmaxf(mx2, __shfl_xor(mx2, 8));
      e0 = __expf(b2_0 - mx2); e1 = __expf(b2_1 - mx2);
      float S2 = e0 + e1;
      S2 += __shfl_xor(S2, 1); S2 += __shfl_xor(S2, 2);
      S2 += __shfl_xor(S2, 4); S2 += __shfl_xor(S2, 8);
      float inv2 = 1.0f / S2;
      c2T[xi * 36 + bl] = e0 * inv2;
      c2T[(xi + 16) * 36 + bl] = e1 * inv2;
    }
    __syncthreads();

    // ---------- Phase D: MFMA + c2-weighted accumulate + W prefetch ----------
    bf16x8 A0 = *(const bf16x8*)&XS[p][dq * 40 + q * 8];
    bf16x8 A1 = *(const bf16x8*)&XS[p][(16 + dq) * 40 + q * 8];
    #pragma unroll
    for (int oo = 0; oo < 4; ++oo) {
      const int o = wv * 4 + oo;
      float w[8] = {wa[oo].x, wa[oo].y, wa[oo].z, wa[oo].w,
                    wb[oo].x, wb[oo].y, wb[oo].z, wb[oo].w};
      bf16x8 Bh, Bl;
      #pragma unroll
      for (int j = 0; j < 8; ++j) {
        unsigned short hi = f2bf(w[j]);
        unsigned short lo = f2bf(w[j] - bf2f(hi));
        Bh[j] = (short)hi;
        Bl[j] = (short)lo;
      }
      f32x4 z = {0.f, 0.f, 0.f, 0.f};
      f32x4 D = __builtin_amdgcn_mfma_f32_16x16x32_bf16(A0, Bl, z, 0, 0, 0);
      D = __builtin_amdgcn_mfma_f32_16x16x32_bf16(A0, Bh, D, 0, 0, 0);
      float4 cv = *(const float4*)&c2T[o * 36 + q * 4];
      acc[oo][0][0] += cv.x * D[0]; acc[oo][0][1] += cv.y * D[1];
      acc[oo][0][2] += cv.z * D[2]; acc[oo][0][3] += cv.w * D[3];
      D = __builtin_amdgcn_mfma_f32_16x16x32_bf16(A1, Bl, z, 0, 0, 0);
      D = __builtin_amdgcn_mfma_f32_16x16x32_bf16(A1, Bh, D, 0, 0, 0);
      cv = *(const float4*)&c2T[o * 36 + 16 + q * 4];
      acc[oo][1][0] += cv.x * D[0]; acc[oo][1][1] += cv.y * D[1];
      acc[oo][1][2] += cv.z * D[2]; acc[oo][1][3] += cv.w * D[3];
      if (nn < NG - 1) {  // reload in place; next use is Phase A's waitcnt
        const float* wp = W + (size_t)(n0 + nn + 1) * 8192 + o * 256 + dq * 16 + qh * 8;
        wa[oo] = *(const float4*)wp;
        wb[oo] = *(const float4*)(wp + 4);
      }
    }
  }

  // ---------- write partials: partial[b][ng][cell] (b-major) ----------
  #pragma unroll
  for (int oo = 0; oo < 4; ++oo) {
    const int o = wv * 4 + oo;
    #pragma unroll
    for (int bb = 0; bb < 2; ++bb) {
      #pragma unroll
      for (int r = 0; r < 4; ++r) {
        const int b_gl = bh * 32 + bb * 16 + q * 4 + r;
        partial[(size_t)b_gl * (256 * 512) + (size_t)ng * 512 + o * 16 + dq]
            = acc[oo][bb][r];
      }
    }
  }
}

// ---------------- reduce 256 group-partials + squash ----------------
__global__ __launch_bounds__(256) void caps_reduce_kernel(
    const float* __restrict__ partial, float* __restrict__ out)
{
  const int t = threadIdx.x;
  const int w4 = t >> 6, ln = t & 63;
  const int pair = blockIdx.x * 4 + w4;     // (b,o), 2048 total
  const int b = pair >> 5, o = pair & 31;
  const int d = ln & 15, cg = ln >> 4;
  const float* p = partial + (size_t)b * (256 * 512) + o * 16 + d;
  float s = 0.f;
  #pragma unroll 8
  for (int gg = cg; gg < 256; gg += 4) s += p[(size_t)gg * 512];
  s += __shfl_xor(s, 16); s += __shfl_xor(s, 32);    // over cg
  float s2 = s * s;
  s2 += __shfl_xor(s2, 1); s2 += __shfl_xor(s2, 2);
  s2 += __shfl_xor(s2, 4); s2 += __shfl_xor(s2, 8);  // over d
  float scale = s2 / (1.0f + s2) / sqrtf(s2 + 1e-7f);
  if (ln < 16) out[(size_t)b * 512 + o * 16 + d] = scale * s;
}

extern "C" void kernel_launch(void* const* d_in, const int* in_sizes, int n_in,
                              void* d_out, int out_size, void* d_ws, size_t ws_size,
                              hipStream_t stream) {
  const float* x = (const float*)d_in[0];   // [64,2048,16]
  const float* W = (const float*)d_in[1];   // [1,2048,32,16,16]
  if (in_sizes[0] != 64 * 2048 * 16) { const float* tmp = x; x = W; W = tmp; }
  float* out = (float*)d_out;               // [64,32,16]

  float* partial = (float*)d_ws;            // 64*256*512 f32 = 32 MB, b-major

  caps_fused_kernel<<<512, 512, 0, stream>>>(x, W, partial);
  caps_reduce_kernel<<<512, 256, 0, stream>>>(partial, out);
}

// Round 4
// 137.237 us; speedup vs baseline: 1.9790x; 1.9790x over previous
//
#include <hip/hip_runtime.h>
#include <cmath>

// CapsuleLayer routing, B=64, Ni=2048, Di=16, No=32, Do=16 (fp32 in/out).
// R4: 3-kernel plan, every pattern individually proven in R1/R3:
//  k1: c2 routing coefficients (R1 math, float4+shuffle W streaming)
//  k2: main GEMM, R1 block structure + split-bf16 MFMA (roles swapped: A=W,
//      B=x so D cols = b and c2-weighting is one scalar per o), gidx-major
//      block-contiguous partial epilogue (the ONLY layout with clean WRITE_SIZE)
//  k3: reduce + squash (unchanged, proven)

#define NI 2048

typedef short bf16x8 __attribute__((ext_vector_type(8)));
typedef float f32x4 __attribute__((ext_vector_type(4)));

static __device__ __forceinline__ unsigned short f2bf(float f) {
  unsigned u = __float_as_uint(f);
  u += 0x7FFFu + ((u >> 16) & 1u);
  return (unsigned short)(u >> 16);
}
static __device__ __forceinline__ float bf2f(unsigned short h) {
  return __uint_as_float(((unsigned)h) << 16);
}
static __device__ __forceinline__ void split4(float4 v, uint2& hi, uint2& lo) {
  unsigned short h0 = f2bf(v.x), h1 = f2bf(v.y), h2 = f2bf(v.z), h3 = f2bf(v.w);
  unsigned short l0 = f2bf(v.x - bf2f(h0)), l1 = f2bf(v.y - bf2f(h1));
  unsigned short l2 = f2bf(v.z - bf2f(h2)), l3 = f2bf(v.w - bf2f(h3));
  hi.x = (unsigned)h0 | ((unsigned)h1 << 16); hi.y = (unsigned)h2 | ((unsigned)h3 << 16);
  lo.x = (unsigned)l0 | ((unsigned)l1 << 16); lo.y = (unsigned)l2 | ((unsigned)l3 << 16);
}

// ---------------- Kernel 1: c2[n][o][b] routing coefficients ----------------
__global__ __launch_bounds__(256) void caps_c2_kernel(
    const float* __restrict__ x, const float* __restrict__ W,
    float* __restrict__ c2g)
{
  const int n = blockIdx.x;
  const int t = threadIdx.x;
  const int wv = t >> 6, l = t & 63;
  __shared__ __align__(16) float WdS[32 * 20];  // [o][i], 80B rows
  __shared__ float xs[64 * 17];                 // [b][i]
  __shared__ float c2s[64 * 33];                // [b][o]

  // Wd[o][i] = sum_d W[n][o][d][i]: float4 per lane, shuffle-reduce over d
  {
    const int d = l >> 2, i4 = l & 3;
    #pragma unroll
    for (int m = 0; m < 8; ++m) {
      const int o = m * 4 + wv;
      float4 v = *(const float4*)(W + (size_t)n * 8192 + o * 256 + d * 16 + i4 * 4);
      float s0 = v.x, s1 = v.y, s2 = v.z, s3 = v.w;
      #pragma unroll
      for (int mk = 4; mk <= 32; mk <<= 1) {
        s0 += __shfl_xor(s0, mk); s1 += __shfl_xor(s1, mk);
        s2 += __shfl_xor(s2, mk); s3 += __shfl_xor(s3, mk);
      }
      if (l < 4) *(float4*)&WdS[o * 20 + l * 4] = make_float4(s0, s1, s2, s3);
    }
  }
  // stage x[b][i] for this n
  {
    const int i = t & 15;
    #pragma unroll
    for (int m = 0; m < 4; ++m) {
      int b = m * 16 + (t >> 4);
      xs[b * 17 + i] = x[(size_t)b * (NI * 16) + n * 16 + i];
    }
  }
  __syncthreads();

  // routing (R1-proven): thread (b = t>>2, oq = t&3), o = oq + 4*jj
  {
    const int b = t >> 2, oq = t & 3;
    float h[8];
    #pragma unroll
    for (int jj = 0; jj < 8; ++jj) {
      const int o = oq + 4 * jj;
      float acc = 0.f;
      #pragma unroll
      for (int i = 0; i < 16; ++i) acc += WdS[o * 20 + i] * xs[b * 17 + i];
      h[jj] = acc;
    }
    float b1[8], e[8];
    float mx = -1e30f;
    #pragma unroll
    for (int jj = 0; jj < 8; ++jj) { b1[jj] = h[jj] * 0.03125f; mx = fmaxf(mx, b1[jj]); }
    mx = fmaxf(mx, __shfl_xor(mx, 1)); mx = fmaxf(mx, __shfl_xor(mx, 2));
    float S = 0.f;
    #pragma unroll
    for (int jj = 0; jj < 8; ++jj) { e[jj] = __expf(b1[jj] - mx); S += e[jj]; }
    S += __shfl_xor(S, 1); S += __shfl_xor(S, 2);
    float inv = 1.0f / S;
    float b2[8]; float mx2 = -1e30f;
    #pragma unroll
    for (int jj = 0; jj < 8; ++jj) { b2[jj] = b1[jj] + e[jj] * inv * h[jj]; mx2 = fmaxf(mx2, b2[jj]); }
    mx2 = fmaxf(mx2, __shfl_xor(mx2, 1)); mx2 = fmaxf(mx2, __shfl_xor(mx2, 2));
    float S2 = 0.f;
    #pragma unroll
    for (int jj = 0; jj < 8; ++jj) { e[jj] = __expf(b2[jj] - mx2); S2 += e[jj]; }
    S2 += __shfl_xor(S2, 1); S2 += __shfl_xor(S2, 2);
    float inv2 = 1.0f / S2;
    #pragma unroll
    for (int jj = 0; jj < 8; ++jj) c2s[b * 33 + oq + 4 * jj] = e[jj] * inv2;
  }
  __syncthreads();
  // write c2g[n][o][b], coalesced
  #pragma unroll
  for (int m = 0; m < 8; ++m) {
    int flat = m * 256 + t;   // o = flat>>6, b = flat&63
    c2g[(size_t)n * 2048 + flat] = c2s[(flat & 63) * 33 + (flat >> 6)];
  }
}

// ---------------- Kernel 2: MFMA main GEMM + weighted accumulate ----------------
// grid 512 = 256 ng x 2 o-halves; block 512 = 8 waves; wave = (bt = wv&3, oct = wv>>2).
// A = [W_hi|W_lo] (m=d, K=32 packed split), B = [x_s;x_s] dup (cols=b), 2 mfmas/tile.
#define WAOFF 0       // WA: rows (o*32 + s*16 + d) * 12 dwords (48B, 16B-aligned)
#define XBOFF 6144    // XB: rows (s*64 + b) * 12
#define C2OFF 7680    // C2L: [o][b] 16*64
__global__ __launch_bounds__(512, 4) void caps_main_kernel(
    const float* __restrict__ x, const float* __restrict__ W,
    const float* __restrict__ c2, float* __restrict__ partial)
{
  const int bx = blockIdx.x;
  const int ng = bx >> 1, hh = bx & 1;
  const int t = threadIdx.x;
  const int wv = t >> 6, l = t & 63;
  const int q = l >> 4, dq = l & 15, qh = q & 1, s_a = q >> 1;
  const int bt = wv & 3, oct = wv >> 2;

  __shared__ __align__(16) float lds[8704];   // 34.8 KB
  float* WA  = lds + WAOFF;
  float* XB  = lds + XBOFF;
  float* C2L = lds + C2OFF;

  float sacc[8][4];
  #pragma unroll
  for (int oo = 0; oo < 8; ++oo)
    { sacc[oo][0] = 0.f; sacc[oo][1] = 0.f; sacc[oo][2] = 0.f; sacc[oo][3] = 0.f; }

  const int n0 = ng * 8;
  // decompositions for staging
  const int wo = t >> 6;            // same as wv: W chunk o for q0=t
  const int wd = (t >> 2) & 15, wi4 = t & 3;
  const int xb = t >> 3, xi = (t & 7) * 2;

  // initial global loads
  float4 wreg0 = *(const float4*)(W + (size_t)n0 * 8192 + hh * 4096 + 4 * t);
  float4 wreg1 = *(const float4*)(W + (size_t)n0 * 8192 + hh * 4096 + 4 * (t + 512));
  float2 xreg  = *(const float2*)(x + (size_t)xb * (NI * 16) + n0 * 16 + xi);
  float2 creg  = *(const float2*)(c2 + (size_t)n0 * 2048 + hh * 1024 + 2 * t);

  #pragma unroll 1
  for (int nn = 0; nn < 8; ++nn) {
    // ---- stage: split to bf16 and write LDS ----
    {
      uint2 hi, lo;
      split4(wreg0, hi, lo);        // q0 = t: (o=wo, d=wd, i4=wi4)
      int row = (wo * 32 + wd) * 12;
      *(uint2*)((char*)&WA[row] + wi4 * 8) = hi;
      *(uint2*)((char*)&WA[row + 16 * 12] + wi4 * 8) = lo;
      split4(wreg1, hi, lo);        // q1 = t+512: o = wo+8
      row = ((wo + 8) * 32 + wd) * 12;
      *(uint2*)((char*)&WA[row] + wi4 * 8) = hi;
      *(uint2*)((char*)&WA[row + 16 * 12] + wi4 * 8) = lo;
      unsigned short h0 = f2bf(xreg.x), h1 = f2bf(xreg.y);
      unsigned short g0 = f2bf(xreg.x - bf2f(h0)), g1 = f2bf(xreg.y - bf2f(h1));
      ((unsigned*)&XB[xb * 12])[xi >> 1]            = (unsigned)h0 | ((unsigned)h1 << 16);
      ((unsigned*)&XB[(64 + xb) * 12])[xi >> 1]     = (unsigned)g0 | ((unsigned)g1 << 16);
      *(float2*)&C2L[2 * t] = creg;
    }
    __syncthreads();

    // ---- prefetch next n (overlaps with MFMA below) ----
    if (nn < 7) {
      const size_t nb = (size_t)(n0 + nn + 1);
      wreg0 = *(const float4*)(W + nb * 8192 + hh * 4096 + 4 * t);
      wreg1 = *(const float4*)(W + nb * 8192 + hh * 4096 + 4 * (t + 512));
      xreg  = *(const float2*)(x + (size_t)xb * (NI * 16) + nb * 16 + xi);
      creg  = *(const float2*)(c2 + nb * 2048 + hh * 1024 + 2 * t);
    }

    // ---- compute: B frags once, loop 8 o's ----
    bf16x8 B0 = *(const bf16x8*)&XB[(bt * 16 + dq) * 12 + qh * 4];        // x_hi
    bf16x8 B1 = *(const bf16x8*)&XB[(64 + bt * 16 + dq) * 12 + qh * 4];   // x_lo
    #pragma unroll
    for (int oo = 0; oo < 8; ++oo) {
      const int o = oct * 8 + oo;
      bf16x8 A = *(const bf16x8*)&WA[(o * 32 + s_a * 16 + dq) * 12 + qh * 4];
      f32x4 D = {0.f, 0.f, 0.f, 0.f};
      D = __builtin_amdgcn_mfma_f32_16x16x32_bf16(A, B0, D, 0, 0, 0);
      D = __builtin_amdgcn_mfma_f32_16x16x32_bf16(A, B1, D, 0, 0, 0);
      float c = C2L[o * 64 + bt * 16 + dq];
      sacc[oo][0] += c * D[0]; sacc[oo][1] += c * D[1];
      sacc[oo][2] += c * D[2]; sacc[oo][3] += c * D[3];
    }
    __syncthreads();
  }

  // ---- epilogue: gidx-major, block-contiguous (the clean-WRITE layout) ----
  // partial[ng][b][cell], cell = (hh*16 + o)*16 + d, d = q*4 + r
  #pragma unroll
  for (int oo = 0; oo < 8; ++oo) {
    const int o = oct * 8 + oo;
    *(float4*)(partial + (size_t)ng * 32768 + (size_t)(bt * 16 + dq) * 512
               + (hh * 16 + o) * 16 + q * 4)
        = make_float4(sacc[oo][0], sacc[oo][1], sacc[oo][2], sacc[oo][3]);
  }
}

// ---------------- Kernel 3: reduce 256 group-partials + squash ----------------
__global__ __launch_bounds__(256) void caps_reduce_kernel(
    const float* __restrict__ partial, float* __restrict__ out)
{
  const int t = threadIdx.x;
  const int w4 = t >> 6, ln = t & 63;
  const int pair = blockIdx.x * 4 + w4;     // (b,o), 2048 total
  const int b = pair >> 5, o = pair & 31;
  const int d = ln & 15, cg = ln >> 4;
  const float* p = partial + (size_t)b * 512 + o * 16 + d;
  float s = 0.f;
  #pragma unroll 8
  for (int gg = cg; gg < 256; gg += 4) s += p[(size_t)gg * 32768];
  s += __shfl_xor(s, 16); s += __shfl_xor(s, 32);    // over cg
  float s2 = s * s;
  s2 += __shfl_xor(s2, 1); s2 += __shfl_xor(s2, 2);
  s2 += __shfl_xor(s2, 4); s2 += __shfl_xor(s2, 8);  // over d
  float scale = s2 / (1.0f + s2) / sqrtf(s2 + 1e-7f);
  if (ln < 16) out[(size_t)b * 512 + o * 16 + d] = scale * s;
}

extern "C" void kernel_launch(void* const* d_in, const int* in_sizes, int n_in,
                              void* d_out, int out_size, void* d_ws, size_t ws_size,
                              hipStream_t stream) {
  const float* x = (const float*)d_in[0];   // [64,2048,16]
  const float* W = (const float*)d_in[1];   // [1,2048,32,16,16]
  if (in_sizes[0] != 64 * 2048 * 16) { const float* tmp = x; x = W; W = tmp; }
  float* out = (float*)d_out;               // [64,32,16]

  float* partial = (float*)d_ws;                     // 256*32768 f32 = 32 MB (gidx-major)
  float* c2g     = partial + (size_t)256 * 32768;    // 2048*2048 f32 = 16 MB, [n][o][b]

  caps_c2_kernel<<<2048, 256, 0, stream>>>(x, W, c2g);
  caps_main_kernel<<<512, 512, 0, stream>>>(x, W, c2g, partial);
  caps_reduce_kernel<<<512, 256, 0, stream>>>(partial, out);
}